// Round 12
// baseline (43.716 us; speedup 1.0000x reference)
//
#include <hip/hip_runtime.h>
#include <math.h>

namespace {

constexpr int kL       = 2048;  // sequence length
constexpr int kThreads = 512;   // 8 waves
constexpr int kBlkPos  = 64;    // 8 waves x 8 positions -> 1024 blocks, ONE round @ 4 blk/CU
constexpr int kPosPerWave = 8;

typedef float    vfloat4 __attribute__((ext_vector_type(4)));
typedef _Float16 half4   __attribute__((ext_vector_type(4)));
typedef _Float16 half2   __attribute__((ext_vector_type(2)));

template <int CTRL, int RM, bool BC>
__device__ __forceinline__ float dpp_step(float x) {
    return __int_as_float(__builtin_amdgcn_update_dpp(0, __float_as_int(x), CTRL, RM, 0xF, BC));
}

// Two independent 64-lane sums, DPP steps interleaved for ILP.
__device__ __forceinline__ void wave_sum2(float& x, float& y) {
    float tx, ty;
    tx = dpp_step<0xB1,  0xF, true >(x);  ty = dpp_step<0xB1,  0xF, true >(y);
    x += tx;                              y += ty;
    tx = dpp_step<0x4E,  0xF, true >(x);  ty = dpp_step<0x4E,  0xF, true >(y);
    x += tx;                              y += ty;
    tx = dpp_step<0x124, 0xF, true >(x);  ty = dpp_step<0x124, 0xF, true >(y);
    x += tx;                              y += ty;
    tx = dpp_step<0x128, 0xF, true >(x);  ty = dpp_step<0x128, 0xF, true >(y);
    x += tx;                              y += ty;
    tx = dpp_step<0x142, 0xA, false>(x);  ty = dpp_step<0x142, 0xA, false>(y);
    x += tx;                              y += ty;
    tx = dpp_step<0x143, 0xC, false>(x);  ty = dpp_step<0x143, 0xC, false>(y);
    x += tx;                              y += ty;
    x = __int_as_float(__builtin_amdgcn_readlane(__float_as_int(x), 63));
    y = __int_as_float(__builtin_amdgcn_readlane(__float_as_int(y), 63));
}

__device__ __forceinline__ half2 vlo(half4 v) { return __builtin_shufflevector(v, v, 0, 1); }
__device__ __forceinline__ half2 vhi(half4 v) { return __builtin_shufflevector(v, v, 2, 3); }

__device__ __forceinline__ int wrow(int t, int c) {  // weight-table row
    return (c == 5) ? 75 : (t * 5 + c);
}

// R12: 32 waves/CU occupancy probe. 76-row fp16 table (38.9 KB -> 4 blocks/CU
// LDS-wise), VGPR<=64 via __launch_bounds__(512,8): fp16 gamma/beta in regs,
// dot2 stats (h stays fp16 through stats). Hot loop structure = R8 (proven).
__global__ __launch_bounds__(kThreads, 8)
void cnn_emb_ln(const int*   __restrict__ ids,     // [B*L] tokens 0..5
                const float* __restrict__ mask,    // [B*L]
                const float* __restrict__ W3,      // [256][5][3]
                const float* __restrict__ W5,      // [256][5][5]
                const float* __restrict__ W7,      // [256][5][7]
                const float* __restrict__ gamma,   // [768]
                const float* __restrict__ beta,    // [768]
                float*       __restrict__ out)     // [B*L][768]
{
    __shared__ half4 sW[76][64];   // 38912 B; row = tap*5+class, row 75 = zeros

    const int tid  = threadIdx.x;
    const int lane = tid & 63;
    const int wave = tid >> 6;

    _Float16* sWh = reinterpret_cast<_Float16*>(sW);
    if (tid < 256) sWh[75 * 256 + tid] = (_Float16)0.f;     // zero sentinel row

    // ---- stage weights: coalesced float4 reads, scattered fp16 LDS writes ----
    {   // W3: 3840 floats, taps 0..2
        const float4* v4 = reinterpret_cast<const float4*>(W3);
        for (int i = tid; i < 960; i += kThreads) {
            const float4 v = v4[i];
            const float f[4] = {v.x, v.y, v.z, v.w};
            #pragma unroll
            for (int j = 0; j < 4; ++j) {
                const int e = 4 * i + j, o = e / 15, r = e % 15;
                sWh[((r % 3) * 5 + (r / 3)) * 256 + o] = (_Float16)f[j];
            }
        }
    }
    {   // W5: 6400 floats, taps 3..7
        const float4* v4 = reinterpret_cast<const float4*>(W5);
        for (int i = tid; i < 1600; i += kThreads) {
            const float4 v = v4[i];
            const float f[4] = {v.x, v.y, v.z, v.w};
            #pragma unroll
            for (int j = 0; j < 4; ++j) {
                const int e = 4 * i + j, o = e / 25, r = e % 25;
                sWh[((3 + r % 5) * 5 + (r / 5)) * 256 + o] = (_Float16)f[j];
            }
        }
    }
    {   // W7: 8960 floats, taps 8..14
        const float4* v4 = reinterpret_cast<const float4*>(W7);
        for (int i = tid; i < 2240; i += kThreads) {
            const float4 v = v4[i];
            const float f[4] = {v.x, v.y, v.z, v.w};
            #pragma unroll
            for (int j = 0; j < 4; ++j) {
                const int e = 4 * i + j, o = e / 35, r = e % 35;
                sWh[((8 + r % 7) * 5 + (r / 7)) * 256 + o] = (_Float16)f[j];
            }
        }
    }

    // ---- per-wave id halo (14) + mask (8) into lane registers ----
    const int p0 = blockIdx.x * kBlkPos + wave * kPosPerWave;
    const int l0 = p0 & (kL - 1);

    int myc = 5;
    if (lane < kPosPerWave + 6) {
        const int lp = l0 - 3 + lane;
        if (lp >= 0 && lp < kL) {
            const int v = ids[p0 - 3 + lane];
            myc = (v < 5) ? v : 5;
        }
    }
    float mym = 0.f;
    if (lane < kPosPerWave) mym = mask[p0 + lane];

    // per-lane gamma/beta as fp16 (12 VGPRs)
    half4 gh[3], bh[3];
    #pragma unroll
    for (int g = 0; g < 3; ++g) {
        const float4 gg = *reinterpret_cast<const float4*>(gamma + g * 256 + 4 * lane);
        const float4 bb = *reinterpret_cast<const float4*>(beta  + g * 256 + 4 * lane);
        gh[g] = half4{(_Float16)gg.x, (_Float16)gg.y, (_Float16)gg.z, (_Float16)gg.w};
        bh[g] = half4{(_Float16)bb.x, (_Float16)bb.y, (_Float16)bb.z, (_Float16)bb.w};
    }

    __syncthreads();

    const half2 ones = {(_Float16)1.f, (_Float16)1.f};
    const float inv_n = 1.0f / 768.0f;

    #pragma unroll
    for (int i = 0; i < kPosPerWave; ++i) {
        int c[7];
        #pragma unroll
        for (int j = 0; j < 7; ++j) c[j] = __builtin_amdgcn_readlane(myc, i + j);
        const float m = __int_as_float(__builtin_amdgcn_readlane(__float_as_int(mym), i));

        const half4 a3 =  sW[wrow(0, c[2])][lane] + sW[wrow(1, c[3])][lane]
                       +  sW[wrow(2, c[4])][lane];
        const half4 a5 = (sW[wrow(3, c[1])][lane] + sW[wrow(4, c[2])][lane])
                       + (sW[wrow(5, c[3])][lane] + sW[wrow(6, c[4])][lane])
                       +  sW[wrow(7, c[5])][lane];
        const half4 a7 = ((sW[wrow( 8, c[0])][lane] + sW[wrow( 9, c[1])][lane])
                       +  (sW[wrow(10, c[2])][lane] + sW[wrow(11, c[3])][lane]))
                       + ((sW[wrow(12, c[4])][lane] + sW[wrow(13, c[5])][lane])
                       +   sW[wrow(14, c[6])][lane]);

        // stats via dot2 (h stays fp16): s = sum(h), q = sum(h^2)
        float s = __builtin_amdgcn_fdot2(vlo(a3), ones, 0.f, false);
        s = __builtin_amdgcn_fdot2(vhi(a3), ones, s, false);
        s = __builtin_amdgcn_fdot2(vlo(a5), ones, s, false);
        s = __builtin_amdgcn_fdot2(vhi(a5), ones, s, false);
        s = __builtin_amdgcn_fdot2(vlo(a7), ones, s, false);
        s = __builtin_amdgcn_fdot2(vhi(a7), ones, s, false);
        float q = __builtin_amdgcn_fdot2(vlo(a3), vlo(a3), 0.f, false);
        q = __builtin_amdgcn_fdot2(vhi(a3), vhi(a3), q, false);
        q = __builtin_amdgcn_fdot2(vlo(a5), vlo(a5), q, false);
        q = __builtin_amdgcn_fdot2(vhi(a5), vhi(a5), q, false);
        q = __builtin_amdgcn_fdot2(vlo(a7), vlo(a7), q, false);
        q = __builtin_amdgcn_fdot2(vhi(a7), vhi(a7), q, false);

        wave_sum2(s, q);

        const float mu  = m * s * inv_n;
        const float ex2 = (m * m) * q * inv_n;
        const float var = fmaxf(ex2 - mu * mu, 0.0f);
        const float rs  = rsqrtf(var + 1e-12f);
        const float aa  = m * rs;          // (m*h - mu)*rs = h*aa + cc
        const float cc  = -mu * rs;

        float* o = out + (size_t)(p0 + i) * 768 + 4 * lane;

        vfloat4 r;
        r.x = fmaf(fmaf((float)a3.x, aa, cc), (float)gh[0].x, (float)bh[0].x);
        r.y = fmaf(fmaf((float)a3.y, aa, cc), (float)gh[0].y, (float)bh[0].y);
        r.z = fmaf(fmaf((float)a3.z, aa, cc), (float)gh[0].z, (float)bh[0].z);
        r.w = fmaf(fmaf((float)a3.w, aa, cc), (float)gh[0].w, (float)bh[0].w);
        *reinterpret_cast<vfloat4*>(o) = r;

        r.x = fmaf(fmaf((float)a5.x, aa, cc), (float)gh[1].x, (float)bh[1].x);
        r.y = fmaf(fmaf((float)a5.y, aa, cc), (float)gh[1].y, (float)bh[1].y);
        r.z = fmaf(fmaf((float)a5.z, aa, cc), (float)gh[1].z, (float)bh[1].z);
        r.w = fmaf(fmaf((float)a5.w, aa, cc), (float)gh[1].w, (float)bh[1].w);
        *reinterpret_cast<vfloat4*>(o + 256) = r;

        r.x = fmaf(fmaf((float)a7.x, aa, cc), (float)gh[2].x, (float)bh[2].x);
        r.y = fmaf(fmaf((float)a7.y, aa, cc), (float)gh[2].y, (float)bh[2].y);
        r.z = fmaf(fmaf((float)a7.z, aa, cc), (float)gh[2].z, (float)bh[2].z);
        r.w = fmaf(fmaf((float)a7.w, aa, cc), (float)gh[2].w, (float)bh[2].w);
        *reinterpret_cast<vfloat4*>(o + 512) = r;
    }
}

} // namespace

extern "C" void kernel_launch(void* const* d_in, const int* in_sizes, int n_in,
                              void* d_out, int out_size, void* d_ws, size_t ws_size,
                              hipStream_t stream) {
    const int*   ids   = (const int*)  d_in[0];
    const float* mask  = (const float*)d_in[1];
    const float* W3    = (const float*)d_in[2];
    const float* W5    = (const float*)d_in[3];
    const float* W7    = (const float*)d_in[4];
    const float* gamma = (const float*)d_in[5];
    const float* beta  = (const float*)d_in[6];
    float*       out   = (float*)d_out;

    const int npos = in_sizes[0];              // B*L = 65536
    const int grid = npos / kBlkPos;           // 1024 blocks; 4/CU -> one clean round

    hipLaunchKernelGGL(cnn_emb_ln, dim3(grid), dim3(kThreads), 0, stream,
                       ids, mask, W3, W5, W7, gamma, beta, out);
}